// Round 8
// baseline (830.515 us; speedup 1.0000x reference)
//
#include <hip/hip_runtime.h>
#include <hip/hip_bf16.h>
#include <math.h>

#define EMB  2048
#define NH   16
#define HD   128
#define SEQ  2048
#define BATCH 2
#define MTOK (BATCH*SEQ)   // 4096 tokens

using bf16x8 = __attribute__((ext_vector_type(8))) __bf16;
using f32x4  = __attribute__((ext_vector_type(4))) float;

__device__ __forceinline__ unsigned short f2bf(float x) {
    unsigned int u = __float_as_uint(x);
    u += 0x7fffu + ((u >> 16) & 1u);   // round-to-nearest-even
    return (unsigned short)(u >> 16);
}

__device__ __forceinline__ float gelu_exact(float x) {
    return 0.5f * x * (1.0f + erff(x * 0.70710678118654752f));
}

// ---------------- flat f32 -> bf16 convert (4 elems/thread) ----------------
__global__ __launch_bounds__(256) void k_conv(const float* __restrict__ in,
                                              unsigned short* __restrict__ out, int n4) {
    int i = blockIdx.x * 256 + threadIdx.x;
    if (i >= n4) return;
    float4 v = ((const float4*)in)[i];
    ushort4 o;
    o.x = f2bf(v.x); o.y = f2bf(v.y); o.z = f2bf(v.z); o.w = f2bf(v.w);
    ((ushort4*)out)[i] = o;
}

// ------------- W[K][N] f32 -> Wt[N][K] bf16 (tiled transpose) ---------------
__global__ __launch_bounds__(256) void k_transconv(const float* __restrict__ W,
                                                   unsigned short* __restrict__ Wt,
                                                   int K, int N) {
    __shared__ float t[32][33];
    int tx = threadIdx.x & 31, ty = threadIdx.x >> 5;   // 32 x 8
    int c0 = blockIdx.x * 32, r0 = blockIdx.y * 32;
    #pragma unroll
    for (int i = 0; i < 4; ++i)
        t[ty + i*8][tx] = W[(size_t)(r0 + ty + i*8) * N + c0 + tx];
    __syncthreads();
    #pragma unroll
    for (int i = 0; i < 4; ++i)
        Wt[(size_t)(c0 + ty + i*8) * K + r0 + tx] = f2bf(t[tx][ty + i*8]);
}

// ------------- 256x256 8-phase bf16 MFMA GEMM (T2+T3+T4+T5) -----------------
// C = A[M,K] @ Bt[N,K]^T.  512 threads = 8 waves (2 wm x 4 wn), wave 128x64.
// BK=64 split into two k-halves; LDS = [buf][khalf][256 rows x 32 k] per
// matrix (128 KB total).  Half-tile (A or B, one k-half, 16 KB, 2 loads/thr)
// is the staging unit.  Per K-tile: 4 phases {ds_read subtile + stage one
// half-tile of tile u+1 into other buf; barrier; lgkmcnt(0); setprio(1);
// 16 MFMA; setprio(0); barrier}.  Counted vmcnt(4) gates before the trailing
// barriers of phases (0,1) and (1,1) -- never drain-0 in steady state.
// Chunk swizzle: position = chunk ^ ((row>>1)&3), inverse pre-applied on the
// global source (both-sides involution).
// EPI: 2 = bf16 GELU(+bias); 5 = f32 partial (no bias); 6 = fused QKV
//      (C0=Q bf16, C1=K bf16, C2=V^T per-head bf16; bias = concat 6144)
template<int EPI, int NSPLIT>
__global__ __launch_bounds__(512, 1) void k_gemm3(const unsigned short* __restrict__ A,
                                                  const unsigned short* __restrict__ Bt,
                                                  const float* __restrict__ bias,
                                                  void* __restrict__ C0,
                                                  void* __restrict__ C1,
                                                  void* __restrict__ C2,
                                                  int M, int N, int Kred, int ldk) {
    __shared__ unsigned short As[2][2][256 * 32];
    __shared__ unsigned short Bs[2][2][256 * 32];
    const int tid = threadIdx.x, lane = tid & 63, wid = tid >> 6;
    const int wm = wid >> 2, wn = wid & 3;              // 2 x 4 waves
    const int nmt = M >> 8, nnt = N >> 8;
    const int nblk = nmt * nnt * NSPLIT, cpx = nblk >> 3;
    const int swz = (blockIdx.x & 7) * cpx + (blockIdx.x >> 3);   // XCD-chunked
    const int bm = swz % nmt;
    const int t2 = swz / nmt;
    const int bn = t2 % nnt, kk2 = t2 / nnt;
    const unsigned short* Ab = A  + (size_t)bm * 256 * ldk + (size_t)kk2 * Kred;
    const unsigned short* Bb = Bt + (size_t)bn * 256 * ldk + (size_t)kk2 * Kred;

    // staging geometry: chunk p in [0,1024), row = p>>2, pos = p&3,
    // logical chunk = pos ^ ((row>>1)&3)  (involution)
    const int sr0 = tid >> 2,        sc0 = (tid & 3) ^ ((sr0 >> 1) & 3);
    const int sr1 = (512 + tid) >> 2, sc1 = ((512 + tid) & 3) ^ ((sr1 >> 1) & 3);

    auto STAGE = [&](const unsigned short* gb, int u, int kh, unsigned short* lds) {
        const int kb = u * 64 + kh * 32;
        __builtin_amdgcn_global_load_lds(
            (const __attribute__((address_space(1))) void*)(gb + (size_t)sr0 * ldk + kb + sc0 * 8),
            (__attribute__((address_space(3))) void*)&lds[(size_t)wid * 64 * 8], 16, 0, 0);
        __builtin_amdgcn_global_load_lds(
            (const __attribute__((address_space(1))) void*)(gb + (size_t)sr1 * ldk + kb + sc1 * 8),
            (__attribute__((address_space(3))) void*)&lds[(size_t)(512 + wid * 64) * 8], 16, 0, 0);
    };

    const int ck   = (((lane >> 4) ^ ((lane >> 1) & 3)) * 8);   // ds_read chunk offset
    const int la15 = lane & 15;

    f32x4 acc[8][4] = {};
    const int NT = Kred >> 6;

    // prologue: tile 0 -> buf 0, gate first k-half, barrier
    STAGE(Ab, 0, 0, &As[0][0][0]);
    STAGE(Bb, 0, 0, &Bs[0][0][0]);
    STAGE(Ab, 0, 1, &As[0][1][0]);
    STAGE(Bb, 0, 1, &Bs[0][1][0]);
    asm volatile("s_waitcnt vmcnt(4)" ::: "memory");
    __builtin_amdgcn_s_barrier();

    for (int u = 0; u < NT; ++u) {
        const int cur = u & 1, nb = cur ^ 1;
        const bool more = (u + 1 < NT);
        bf16x8 af[8], bfr[4];

        // ---- phase (0,0): ds_read A-k0 (8) + B-k0 nh0 (2); stage A-k0(u+1)
        #pragma unroll
        for (int mi = 0; mi < 8; ++mi)
            af[mi] = *(const bf16x8*)&As[cur][0][(wm*128 + mi*16 + la15)*32 + ck];
        bfr[0] = *(const bf16x8*)&Bs[cur][0][(wn*64 +  0 + la15)*32 + ck];
        bfr[1] = *(const bf16x8*)&Bs[cur][0][(wn*64 + 16 + la15)*32 + ck];
        if (more) STAGE(Ab, u + 1, 0, &As[nb][0][0]);
        __builtin_amdgcn_sched_barrier(0);
        __builtin_amdgcn_s_barrier();
        asm volatile("s_waitcnt lgkmcnt(0)" ::: "memory");
        __builtin_amdgcn_sched_barrier(0);
        __builtin_amdgcn_s_setprio(1);
        #pragma unroll
        for (int mi = 0; mi < 8; ++mi) {
            acc[mi][0] = __builtin_amdgcn_mfma_f32_16x16x32_bf16(af[mi], bfr[0], acc[mi][0], 0, 0, 0);
            acc[mi][1] = __builtin_amdgcn_mfma_f32_16x16x32_bf16(af[mi], bfr[1], acc[mi][1], 0, 0, 0);
        }
        __builtin_amdgcn_s_setprio(0);
        __builtin_amdgcn_sched_barrier(0);
        __builtin_amdgcn_s_barrier();

        // ---- phase (0,1): ds_read B-k0 nh1 (2); stage B-k0(u+1)
        bfr[2] = *(const bf16x8*)&Bs[cur][0][(wn*64 + 32 + la15)*32 + ck];
        bfr[3] = *(const bf16x8*)&Bs[cur][0][(wn*64 + 48 + la15)*32 + ck];
        if (more) STAGE(Bb, u + 1, 0, &Bs[nb][0][0]);
        __builtin_amdgcn_sched_barrier(0);
        __builtin_amdgcn_s_barrier();
        asm volatile("s_waitcnt lgkmcnt(0)" ::: "memory");
        __builtin_amdgcn_sched_barrier(0);
        __builtin_amdgcn_s_setprio(1);
        #pragma unroll
        for (int mi = 0; mi < 8; ++mi) {
            acc[mi][2] = __builtin_amdgcn_mfma_f32_16x16x32_bf16(af[mi], bfr[2], acc[mi][2], 0, 0, 0);
            acc[mi][3] = __builtin_amdgcn_mfma_f32_16x16x32_bf16(af[mi], bfr[3], acc[mi][3], 0, 0, 0);
        }
        __builtin_amdgcn_s_setprio(0);
        __builtin_amdgcn_sched_barrier(0);
        if (more) asm volatile("s_waitcnt vmcnt(4)" ::: "memory");   // gate A-k1,B-k1(u)
        else      asm volatile("s_waitcnt vmcnt(0)" ::: "memory");
        __builtin_amdgcn_s_barrier();

        // ---- phase (1,0): ds_read A-k1 (8) + B-k1 nh0 (2); stage A-k1(u+1)
        #pragma unroll
        for (int mi = 0; mi < 8; ++mi)
            af[mi] = *(const bf16x8*)&As[cur][1][(wm*128 + mi*16 + la15)*32 + ck];
        bfr[0] = *(const bf16x8*)&Bs[cur][1][(wn*64 +  0 + la15)*32 + ck];
        bfr[1] = *(const bf16x8*)&Bs[cur][1][(wn*64 + 16 + la15)*32 + ck];
        if (more) STAGE(Ab, u + 1, 1, &As[nb][1][0]);
        __builtin_amdgcn_sched_barrier(0);
        __builtin_amdgcn_s_barrier();
        asm volatile("s_waitcnt lgkmcnt(0)" ::: "memory");
        __builtin_amdgcn_sched_barrier(0);
        __builtin_amdgcn_s_setprio(1);
        #pragma unroll
        for (int mi = 0; mi < 8; ++mi) {
            acc[mi][0] = __builtin_amdgcn_mfma_f32_16x16x32_bf16(af[mi], bfr[0], acc[mi][0], 0, 0, 0);
            acc[mi][1] = __builtin_amdgcn_mfma_f32_16x16x32_bf16(af[mi], bfr[1], acc[mi][1], 0, 0, 0);
        }
        __builtin_amdgcn_s_setprio(0);
        __builtin_amdgcn_sched_barrier(0);
        __builtin_amdgcn_s_barrier();

        // ---- phase (1,1): ds_read B-k1 nh1 (2); stage B-k1(u+1)
        bfr[2] = *(const bf16x8*)&Bs[cur][1][(wn*64 + 32 + la15)*32 + ck];
        bfr[3] = *(const bf16x8*)&Bs[cur][1][(wn*64 + 48 + la15)*32 + ck];
        if (more) STAGE(Bb, u + 1, 1, &Bs[nb][1][0]);
        __builtin_amdgcn_sched_barrier(0);
        __builtin_amdgcn_s_barrier();
        asm volatile("s_waitcnt lgkmcnt(0)" ::: "memory");
        __builtin_amdgcn_sched_barrier(0);
        __builtin_amdgcn_s_setprio(1);
        #pragma unroll
        for (int mi = 0; mi < 8; ++mi) {
            acc[mi][2] = __builtin_amdgcn_mfma_f32_16x16x32_bf16(af[mi], bfr[2], acc[mi][2], 0, 0, 0);
            acc[mi][3] = __builtin_amdgcn_mfma_f32_16x16x32_bf16(af[mi], bfr[3], acc[mi][3], 0, 0, 0);
        }
        __builtin_amdgcn_s_setprio(0);
        __builtin_amdgcn_sched_barrier(0);
        asm volatile("s_waitcnt vmcnt(4)" ::: "memory");             // gate A-k0,B-k0(u+1)
        __builtin_amdgcn_s_barrier();
    }

    const int row0b = bm*256 + wm*128, col0 = bn*256 + wn*64;
    #pragma unroll
    for (int mi = 0; mi < 8; ++mi) {
        #pragma unroll
        for (int ni = 0; ni < 4; ++ni) {
            const int c = col0 + ni*16 + la15;
            const int r0 = row0b + mi*16 + (lane >> 4) * 4;
            if (EPI == 5) {
                float* out = (float*)C0 + (size_t)kk2 * M * N;
                #pragma unroll
                for (int j = 0; j < 4; ++j)
                    out[(size_t)(r0+j) * N + c] = acc[mi][ni][j];
            } else if (EPI == 2) {
                const float bv = bias[c];
                #pragma unroll
                for (int j = 0; j < 4; ++j)
                    ((unsigned short*)C0)[(size_t)(r0+j) * N + c] = f2bf(gelu_exact(acc[mi][ni][j] + bv));
            } else {  // EPI == 6: fused QKV epilogue
                const float bv = bias[c];
                const int seg = c >> 11;           // 0=Q, 1=K, 2=V
                if (seg == 0) {
                    #pragma unroll
                    for (int j = 0; j < 4; ++j)
                        ((unsigned short*)C0)[(size_t)(r0+j) * EMB + c] = f2bf(acc[mi][ni][j] + bv);
                } else if (seg == 1) {
                    #pragma unroll
                    for (int j = 0; j < 4; ++j)
                        ((unsigned short*)C1)[(size_t)(r0+j) * EMB + (c - 2048)] = f2bf(acc[mi][ni][j] + bv);
                } else {
                    const int cc = c - 4096;
                    const int hh = cc >> 7, dd = cc & 127;
                    const int bb2 = r0 >> 11, s0 = r0 & 2047;
                    ushort4 uo;
                    uo.x = f2bf(acc[mi][ni][0] + bv); uo.y = f2bf(acc[mi][ni][1] + bv);
                    uo.z = f2bf(acc[mi][ni][2] + bv); uo.w = f2bf(acc[mi][ni][3] + bv);
                    *(ushort4*)((unsigned short*)C2 +
                                ((size_t)((bb2*NH + hh)*HD + dd) * SEQ + s0)) = uo;
                }
            }
        }
    }
}

// ------------- MFMA flash attention, KV-split partials (bf16, causal) -------
__global__ __launch_bounds__(256, 4) void k_attn_part(const unsigned short* __restrict__ Qb,
                                                      const unsigned short* __restrict__ Kb,
                                                      const unsigned short* __restrict__ VTb,
                                                      float* __restrict__ Opart,
                                                      float* __restrict__ Ml) {
    const int tid = threadIdx.x;
    const int lane = tid & 63, w = tid >> 6;
    const int g = lane >> 4, c = lane & 15;
    const int bid = blockIdx.x;
    const int swz = (bid & 7) * 512 + (bid >> 3);
    const int bh = swz >> 7;
    const int b = bh >> 4, h = bh & 15;
    const int rr = swz & 127;
    const int qt = rr >> 2, ks = rr & 3;
    const int nt = qt + 1;
    const int t0 = (nt * ks) >> 2, t1 = (nt * (ks + 1)) >> 2;
    const int qb = qt * 64 + w * 16;

    __shared__ unsigned short Ks[64 * 128];
    __shared__ unsigned short Vs[128 * 64];
    __shared__ unsigned short p_lds[4][16 * 64];

    bf16x8 qf[4];
    {
        const unsigned short* qrow = Qb + (size_t)(b*SEQ + qb + c) * EMB + h*HD;
        #pragma unroll
        for (int dch = 0; dch < 4; ++dch)
            qf[dch] = *(const bf16x8*)(qrow + dch*32 + g*8);
    }

    f32x4 o[8];
    #pragma unroll
    for (int ni = 0; ni < 8; ++ni) o[ni] = (f32x4){0.f, 0.f, 0.f, 0.f};
    float m_c = -1e30f, l_c = 0.f;

    const int q = qb + c;
    const int qmaxw = qb + 15;
    const unsigned short* Kbase = Kb  + (size_t)(b*SEQ) * EMB + h*HD;
    const unsigned short* Vbase = VTb + (size_t)((b*NH + h) * HD) * SEQ;
    const float scale = 0.08838834764831845f;
    char* pw = (char*)&p_lds[w][0];

    for (int ti = t0; ti < t1; ++ti) {
        const int tc = ti * 64;
        #pragma unroll
        for (int it = 0; it < 4; ++it) {
            const int cl = it * 256 + tid;
            const unsigned short* gk = Kbase + (size_t)(tc + (cl >> 4)) * EMB
                                     + (((cl & 15) ^ ((cl >> 4) & 7)) * 8);
            __builtin_amdgcn_global_load_lds(
                (const __attribute__((address_space(1))) void*)gk,
                (__attribute__((address_space(3))) void*)&Ks[(it*256 + w*64) * 8], 16, 0, 0);
            const unsigned short* gv = Vbase + (size_t)(cl >> 3) * SEQ + tc
                                     + (((cl & 7) ^ ((cl >> 3) & 7)) * 8);
            __builtin_amdgcn_global_load_lds(
                (const __attribute__((address_space(1))) void*)gv,
                (__attribute__((address_space(3))) void*)&Vs[(it*256 + w*64) * 8], 16, 0, 0);
        }
        __syncthreads();

        f32x4 sc[4];
        #pragma unroll
        for (int kt = 0; kt < 4; ++kt) {
            sc[kt] = (f32x4){0.f, 0.f, 0.f, 0.f};
            if (tc + kt*16 <= qmaxw) {
                #pragma unroll
                for (int dch = 0; dch < 4; ++dch) {
                    bf16x8 kf = *(const bf16x8*)&Ks[(kt*16 + c)*128 + (((dch*4 + g) ^ (c & 7)) * 8)];
                    sc[kt] = __builtin_amdgcn_mfma_f32_16x16x32_bf16(kf, qf[dch], sc[kt], 0, 0, 0);
                }
            }
        }
        float mx = -1e30f;
        #pragma unroll
        for (int kt = 0; kt < 4; ++kt)
            #pragma unroll
            for (int j = 0; j < 4; ++j) {
                const int key = tc + kt*16 + g*4 + j;
                const float s = (key <= q) ? sc[kt][j] * scale : -1e30f;
                mx = fmaxf(mx, s);
            }
        mx = fmaxf(mx, __shfl_xor(mx, 16));
        mx = fmaxf(mx, __shfl_xor(mx, 32));
        if (!__all(mx <= m_c + 8.f)) {
            const float mn = fmaxf(m_c, mx);
            const float corr = __expf(m_c - mn);
            l_c *= corr;
            m_c = mn;
            #pragma unroll
            for (int j = 0; j < 4; ++j) {
                const float cj = __shfl(corr, g*4 + j);
                #pragma unroll
                for (int ni = 0; ni < 8; ++ni) o[ni][j] *= cj;
            }
        }
        float ps = 0.f;
        #pragma unroll
        for (int kt = 0; kt < 4; ++kt) {
            float p[4];
            #pragma unroll
            for (int j = 0; j < 4; ++j) {
                const int key = tc + kt*16 + g*4 + j;
                const float s = (key <= q) ? sc[kt][j] * scale : -1e30f;
                p[j] = __expf(s - m_c);
                ps += p[j];
            }
            uint2 pk;
            pk.x = (unsigned int)f2bf(p[0]) | ((unsigned int)f2bf(p[1]) << 16);
            pk.y = (unsigned int)f2bf(p[2]) | ((unsigned int)f2bf(p[3]) << 16);
            const int byte = (c*128 + kt*32 + g*8) ^ ((c & 7) << 4);
            *(uint2*)(pw + byte) = pk;
        }
        ps += __shfl_xor(ps, 16);
        ps += __shfl_xor(ps, 32);
        l_c += ps;
        asm volatile("s_waitcnt lgkmcnt(0)" ::: "memory");
        __builtin_amdgcn_sched_barrier(0);
        #pragma unroll
        for (int kc = 0; kc < 2; ++kc) {
            if (tc + kc*32 <= qmaxw) {
                const int byte = (c*128 + kc*64 + g*16) ^ ((c & 7) << 4);
                bf16x8 pa = *(const bf16x8*)(pw + byte);
                #pragma unroll
                for (int ni = 0; ni < 8; ++ni) {
                    bf16x8 vf = *(const bf16x8*)&Vs[(ni*16 + c)*64 + (((kc*4 + g) ^ (c & 7)) * 8)];
                    o[ni] = __builtin_amdgcn_mfma_f32_16x16x32_bf16(pa, vf, o[ni], 0, 0, 0);
                }
            }
        }
        __syncthreads();
    }

    const int slot = ((b*NH + h) * 32 + qt) * 4 + ks;
    float* op = Opart + (size_t)slot * (64 * 128);
    #pragma unroll
    for (int ni = 0; ni < 8; ++ni)
        #pragma unroll
        for (int j = 0; j < 4; ++j)
            op[(size_t)(w*16 + g*4 + j) * 128 + ni*16 + c] = o[ni][j];
    if (lane < 16) {
        Ml[(size_t)slot * 128 +      w*16 + lane] = m_c;
        Ml[(size_t)slot * 128 + 64 + w*16 + lane] = l_c;
    }
}

// ------------- combine KV-split partials (4 slots) -> bf16 ctx ---------------
__global__ __launch_bounds__(256) void k_attn_reduce(const float* __restrict__ Opart,
                                                     const float* __restrict__ Ml,
                                                     unsigned short* __restrict__ Ob) {
    const int qt = blockIdx.x, h = blockIdx.y, b = blockIdx.z;
    const int slot0 = ((b*NH + h) * 32 + qt) * 4;
    const int row = threadIdx.x >> 2;
    const int c0 = (threadIdx.x & 3) * 32;
    float M = -1e30f;
    #pragma unroll
    for (int s = 0; s < 4; ++s)
        M = fmaxf(M, Ml[(size_t)(slot0 + s) * 128 + row]);
    float L = 0.f;
    float wgt[4];
    #pragma unroll
    for (int s = 0; s < 4; ++s) {
        wgt[s] = __expf(Ml[(size_t)(slot0 + s) * 128 + row] - M);
        L += Ml[(size_t)(slot0 + s) * 128 + 64 + row] * wgt[s];
    }
    float acc[32];
    #pragma unroll
    for (int k = 0; k < 32; ++k) acc[k] = 0.f;
    #pragma unroll
    for (int s = 0; s < 4; ++s) {
        const float4* op = (const float4*)(Opart + ((size_t)(slot0 + s) * 64 + row) * 128 + c0);
        #pragma unroll
        for (int q4 = 0; q4 < 8; ++q4) {
            float4 v = op[q4];
            acc[q4*4+0] += v.x * wgt[s]; acc[q4*4+1] += v.y * wgt[s];
            acc[q4*4+2] += v.z * wgt[s]; acc[q4*4+3] += v.w * wgt[s];
        }
    }
    const float inv = 1.0f / L;
    unsigned short* orow = Ob + (size_t)(b*SEQ + qt*64 + row) * EMB + h*HD + c0;
    #pragma unroll
    for (int q4 = 0; q4 < 8; ++q4) {
        ushort4 u;
        u.x = f2bf(acc[q4*4+0] * inv); u.y = f2bf(acc[q4*4+1] * inv);
        u.z = f2bf(acc[q4*4+2] * inv); u.w = f2bf(acc[q4*4+3] * inv);
        ((ushort4*)orow)[q4] = u;
    }
}

// ------- row LayerNorm over 2048 with fused input combine -------------------
__global__ __launch_bounds__(256) void k_ln(const float* __restrict__ X0,
                                            const float* __restrict__ X1,
                                            const float* __restrict__ bias,
                                            const float* __restrict__ res,
                                            const float* __restrict__ g,
                                            const float* __restrict__ be,
                                            float* __restrict__ Of32,
                                            unsigned short* __restrict__ Obf16) {
    const int row = blockIdx.x;
    float4 v[2];
    float s = 0.f, ss = 0.f;
    #pragma unroll
    for (int i = 0; i < 2; ++i) {
        const int c4 = threadIdx.x + i*256;
        float4 a = ((const float4*)(X0 + (size_t)row * EMB))[c4];
        if (X1) {
            float4 b1v = ((const float4*)(X1 + (size_t)row * EMB))[c4];
            a.x += b1v.x; a.y += b1v.y; a.z += b1v.z; a.w += b1v.w;
        }
        if (bias) {
            float4 bv = ((const float4*)bias)[c4];
            a.x += bv.x; a.y += bv.y; a.z += bv.z; a.w += bv.w;
        }
        if (res) {
            float4 rv = ((const float4*)(res + (size_t)row * EMB))[c4];
            a.x += rv.x; a.y += rv.y; a.z += rv.z; a.w += rv.w;
        }
        v[i] = a;
        s  += a.x + a.y + a.z + a.w;
        ss += a.x*a.x + a.y*a.y + a.z*a.z + a.w*a.w;
    }
    #pragma unroll
    for (int o = 32; o; o >>= 1) { s += __shfl_xor(s, o); ss += __shfl_xor(ss, o); }
    __shared__ float red[2][4];
    const int lane = threadIdx.x & 63, wid = threadIdx.x >> 6;
    if (lane == 0) { red[0][wid] = s; red[1][wid] = ss; }
    __syncthreads();
    s  = red[0][0] + red[0][1] + red[0][2] + red[0][3];
    ss = red[1][0] + red[1][1] + red[1][2] + red[1][3];
    const float mu = s * (1.0f / EMB);
    const float var = ss * (1.0f / EMB) - mu * mu;
    const float rs = rsqrtf(var + 1e-5f);
    #pragma unroll
    for (int i = 0; i < 2; ++i) {
        const int c4 = threadIdx.x + i*256;
        float4 gv = ((const float4*)g)[c4];
        float4 bv = ((const float4*)be)[c4];
        float4 y;
        y.x = (v[i].x - mu) * rs * gv.x + bv.x;
        y.y = (v[i].y - mu) * rs * gv.y + bv.y;
        y.z = (v[i].z - mu) * rs * gv.z + bv.z;
        y.w = (v[i].w - mu) * rs * gv.w + bv.w;
        if (Of32)  ((float4*)(Of32 + (size_t)row * EMB))[c4] = y;
        if (Obf16) {
            ushort4 u; u.x = f2bf(y.x); u.y = f2bf(y.y); u.z = f2bf(y.z); u.w = f2bf(y.w);
            ((ushort4*)(Obf16 + (size_t)row * EMB))[c4] = u;
        }
    }
}

extern "C" void kernel_launch(void* const* d_in, const int* in_sizes, int n_in,
                              void* d_out, int out_size, void* d_ws, size_t ws_size,
                              hipStream_t stream) {
    const float* emb = (const float*)d_in[0];
    const float* Wq  = (const float*)d_in[1];  const float* bq  = (const float*)d_in[2];
    const float* Wk  = (const float*)d_in[3];  const float* bk  = (const float*)d_in[4];
    const float* Wv  = (const float*)d_in[5];  const float* bv  = (const float*)d_in[6];
    const float* Wfc = (const float*)d_in[7];  const float* bfc = (const float*)d_in[8];
    const float* g1  = (const float*)d_in[9];  const float* be1 = (const float*)d_in[10];
    const float* W1  = (const float*)d_in[11]; const float* b1  = (const float*)d_in[12];
    const float* W2  = (const float*)d_in[13]; const float* b2  = (const float*)d_in[14];
    const float* g2  = (const float*)d_in[15]; const float* be2 = (const float*)d_in[16];

    char* ws = (char*)d_ws;
    unsigned short* aB   = (unsigned short*)(ws + (size_t)  0 * (1u<<20));
    unsigned short* ln1B = (unsigned short*)(ws + (size_t) 16 * (1u<<20));
    unsigned short* WtB  = (unsigned short*)(ws + (size_t) 32 * (1u<<20));
    float*          Ml   = (float*)         (ws + (size_t) 32 * (1u<<20));
    unsigned short* hB   = (unsigned short*)(ws + (size_t) 64 * (1u<<20));
    unsigned short* Qb   = (unsigned short*)(ws + (size_t) 64 * (1u<<20));
    unsigned short* Kb   = (unsigned short*)(ws + (size_t) 80 * (1u<<20));
    unsigned short* VTb  = (unsigned short*)(ws + (size_t) 96 * (1u<<20));
    float*          Opart= (float*)         (ws + (size_t)112 * (1u<<20));
    float*          pA   = (float*)         (ws + (size_t)128 * (1u<<20));
    float*          ln1f = (float*)         (ws + (size_t)192 * (1u<<20));
    float*          bias6= (float*)         (ws + (size_t)236 * (1u<<20));

    const dim3 blk(256);
    const dim3 blk2(512);
    const int n4 = MTOK * EMB / 4;

    // embeddings -> bf16; assemble fused QKV bias
    k_conv<<<dim3(n4 / 256), blk, 0, stream>>>(emb, aB, n4);
    hipMemcpyAsync(bias6,        bq, EMB*sizeof(float), hipMemcpyDeviceToDevice, stream);
    hipMemcpyAsync(bias6 + EMB,  bk, EMB*sizeof(float), hipMemcpyDeviceToDevice, stream);
    hipMemcpyAsync(bias6 + 2*EMB,bv, EMB*sizeof(float), hipMemcpyDeviceToDevice, stream);

    // fused QKV: Wt = [6144][2048]
    k_transconv<<<dim3(EMB/32, EMB/32), blk, 0, stream>>>(Wq, WtB,              EMB, EMB);
    k_transconv<<<dim3(EMB/32, EMB/32), blk, 0, stream>>>(Wk, WtB + EMB*EMB,    EMB, EMB);
    k_transconv<<<dim3(EMB/32, EMB/32), blk, 0, stream>>>(Wv, WtB + 2*EMB*EMB,  EMB, EMB);
    k_gemm3<6,1><<<dim3((MTOK/256)*(3*EMB/256)), blk2, 0, stream>>>(
        aB, WtB, bias6, Qb, Kb, VTb, MTOK, 3*EMB, EMB, EMB);

    // KV-split MFMA flash attention -> partials -> ctx bf16 (overwrites aB)
    k_attn_part<<<dim3(4096), blk, 0, stream>>>(Qb, Kb, VTb, Opart, Ml);
    k_attn_reduce<<<dim3(SEQ/64, NH, BATCH), blk, 0, stream>>>(Opart, Ml, aB);

    // Wfc split-K x2 -> pA/pB; LN1 fuses +bfc+emb
    k_transconv<<<dim3(EMB/32, EMB/32), blk, 0, stream>>>(Wfc, WtB, EMB, EMB);
    k_gemm3<5,2><<<dim3((MTOK/256)*(EMB/256)*2), blk2, 0, stream>>>(
        aB, WtB, nullptr, pA, nullptr, nullptr, MTOK, EMB, EMB/2, EMB);
    k_ln<<<dim3(MTOK), blk, 0, stream>>>(pA, pA + (size_t)MTOK*EMB, bfc, emb, g1, be1, ln1f, ln1B);

    // h = gelu(ln1 @ W1 + b1) -> hB
    k_transconv<<<dim3(4*EMB/32, EMB/32), blk, 0, stream>>>(W1, WtB, EMB, 4*EMB);
    k_gemm3<2,1><<<dim3((MTOK/256)*(4*EMB/256)), blk2, 0, stream>>>(
        ln1B, WtB, b1, hB, nullptr, nullptr, MTOK, 4*EMB, EMB, EMB);

    // W2 split-K x2 -> pA/pB; LN2 fuses +b2+ln1f -> d_out
    k_transconv<<<dim3(EMB/32, (4*EMB)/32), blk, 0, stream>>>(W2, WtB, 4*EMB, EMB);
    k_gemm3<5,2><<<dim3((MTOK/256)*(EMB/256)*2), blk2, 0, stream>>>(
        hB, WtB, nullptr, pA, nullptr, nullptr, MTOK, EMB, 2*EMB, 4*EMB);
    k_ln<<<dim3(MTOK), blk, 0, stream>>>(pA, pA + (size_t)MTOK*EMB, b2, ln1f, g2, be2, (float*)d_out, nullptr);
}